// Round 9
// baseline (578.871 us; speedup 1.0000x reference)
//
#include <hip/hip_runtime.h>
#include <hip/hip_bf16.h>

#define N_NODES_C  100000
#define N_EDGES_C  1600000
#define IN_FEATS_C 128
#define OUT_FEATS_C 32
#define NEG_SLOPE_C 0.2f

#define BNODES_LOG 6
#define BNODES     64                               // dst nodes per bucket
#define NB         ((N_NODES_C + BNODES - 1) >> BNODES_LOG)   // 1563 buckets
#define BCAP       4096                             // mean 1024, sigma~32 -> +96 sigma
#define SRC_MASK   0x1FFFFu                         // src < 2^17 (100000)

typedef __attribute__((ext_vector_type(8))) short short8;
typedef __attribute__((ext_vector_type(4))) float f32x4;

// Static device scratch (~33 MB) — no assumption about ws_size.
__device__ __hip_bfloat16 g_zb[N_NODES_C * OUT_FEATS_C];  // bf16 z: 64B/row = 1 line/edge
__device__ float    g_el[N_NODES_C];
__device__ float    g_er[N_NODES_C];
__device__ int      g_bcnt[NB];                 // per-bucket edge count
__device__ unsigned g_brec[NB][BCAP];           // packed records: src | dst_local<<17
__device__ short8   g_wf_hi[2][4][64];          // W MFMA B-fragments (bf16 hi)
__device__ short8   g_wf_lo[2][4][64];          // ... lo part (hi+lo split ~ f32 accuracy)

static __device__ __forceinline__ unsigned short f2bf(float x) {
    unsigned int u = __float_as_uint(x);
    unsigned int r = (u + 0x7FFFu + ((u >> 16) & 1u)) >> 16;
    return (unsigned short)r;
}
static __device__ __forceinline__ float bf2f(unsigned short h) {
    return __uint_as_float(((unsigned int)h) << 16);
}

// ---------------- Kernel 0: W -> MFMA fragments + zero bucket counters ----------------
__global__ __launch_bounds__(256) void k_wt(const float* __restrict__ W)
{
    int i = blockIdx.x * 256 + threadIdx.x;
    if (i < NB) g_bcnt[i] = 0;                  // re-init every call
    if (i >= 512) return;
    int lane = i & 63;
    int kt   = (i >> 6) & 3;
    int nt   = i >> 8;
    int row  = nt * 16 + (lane & 15);
    const float* p = W + (size_t)row * IN_FEATS_C + kt * 32 + (lane >> 4) * 8;
    float4 x0 = *(const float4*)(p);
    float4 x1 = *(const float4*)(p + 4);
    float xs[8] = {x0.x, x0.y, x0.z, x0.w, x1.x, x1.y, x1.z, x1.w};
    short8 hi, lo;
#pragma unroll
    for (int j = 0; j < 8; ++j) {
        unsigned short hb = f2bf(xs[j]);
        hi[j] = (short)hb;
        lo[j] = (short)f2bf(xs[j] - bf2f(hb));
    }
    g_wf_hi[nt][kt][lane] = hi;
    g_wf_lo[nt][kt][lane] = lo;
}

// ---------------- Kernel 1: MFMA projection (unchanged from R8) ----------------
__global__ __launch_bounds__(256) void k_project(const float* __restrict__ h,
                                                 const float* __restrict__ a,
                                                 int n_nodes)
{
    int tile = (blockIdx.x * 256 + threadIdx.x) >> 6;
    int l    = threadIdx.x & 63;
    int ntiles = (n_nodes + 15) / 16;
    if (tile >= ntiles) return;
    int r16 = l & 15;
    int g   = l >> 4;

    const float* hrow = h + (size_t)(tile * 16 + r16) * IN_FEATS_C + g * 8;
    f32x4 acc0 = {0.f, 0.f, 0.f, 0.f};
    f32x4 acc1 = {0.f, 0.f, 0.f, 0.f};

#pragma unroll
    for (int kt = 0; kt < 4; ++kt) {
        float4 x0 = *(const float4*)(hrow + kt * 32);
        float4 x1 = *(const float4*)(hrow + kt * 32 + 4);
        float xs[8] = {x0.x, x0.y, x0.z, x0.w, x1.x, x1.y, x1.z, x1.w};
        short8 ahi, alo;
#pragma unroll
        for (int j = 0; j < 8; ++j) {
            unsigned short hb = f2bf(xs[j]);
            ahi[j] = (short)hb;
            alo[j] = (short)f2bf(xs[j] - bf2f(hb));
        }
        short8 bh0 = g_wf_hi[0][kt][l], bl0 = g_wf_lo[0][kt][l];
        short8 bh1 = g_wf_hi[1][kt][l], bl1 = g_wf_lo[1][kt][l];
        acc0 = __builtin_amdgcn_mfma_f32_16x16x32_bf16(ahi, bh0, acc0, 0, 0, 0);
        acc0 = __builtin_amdgcn_mfma_f32_16x16x32_bf16(alo, bh0, acc0, 0, 0, 0);
        acc0 = __builtin_amdgcn_mfma_f32_16x16x32_bf16(ahi, bl0, acc0, 0, 0, 0);
        acc1 = __builtin_amdgcn_mfma_f32_16x16x32_bf16(ahi, bh1, acc1, 0, 0, 0);
        acc1 = __builtin_amdgcn_mfma_f32_16x16x32_bf16(alo, bh1, acc1, 0, 0, 0);
        acc1 = __builtin_amdgcn_mfma_f32_16x16x32_bf16(ahi, bl1, acc1, 0, 0, 0);
    }

    float al0 = a[r16], al1 = a[16 + r16];
    float ar0 = a[32 + r16], ar1 = a[48 + r16];
    float elp[4], erp[4];
    unsigned short* zb = (unsigned short*)g_zb;
#pragma unroll
    for (int r = 0; r < 4; ++r) {
        float z0 = acc0[r], z1 = acc1[r];
        int node = tile * 16 + g * 4 + r;
        zb[(size_t)node * OUT_FEATS_C + r16]      = f2bf(z0);
        zb[(size_t)node * OUT_FEATS_C + 16 + r16] = f2bf(z1);
        elp[r] = z0 * al0 + z1 * al1;
        erp[r] = z0 * ar0 + z1 * ar1;
    }
#pragma unroll
    for (int m = 1; m <= 8; m <<= 1) {
#pragma unroll
        for (int r = 0; r < 4; ++r) {
            elp[r] += __shfl_xor(elp[r], m, 64);
            erp[r] += __shfl_xor(erp[r], m, 64);
        }
    }
    int nodeb = tile * 16 + g * 4;
    if (r16 == 0) {
#pragma unroll
        for (int r = 0; r < 4; ++r) g_el[nodeb + r] = elp[r];
    } else if (r16 == 1) {
#pragma unroll
        for (int r = 0; r < 4; ++r) g_er[nodeb + r] = erp[r];
    }
}

// ---------------- Kernel 2: bucket edges by dst ----------------
// ONE atomic per edge on NB=1563 hot counters; record writes go to monotone
// per-bucket frontiers (1563 x 64B hot lines, L2-resident -> writes merge).
// Record = src | dst_local<<17 (23 bits). Sequentially readable by gather.
__global__ __launch_bounds__(256) void k_bucket(const int* __restrict__ src,
                                                const int* __restrict__ dst, int n_edges)
{
    int e = blockIdx.x * blockDim.x + threadIdx.x;
    if (e < n_edges) {
        int d = dst[e];
        int b = d >> BNODES_LOG;
        int pos = atomicAdd(&g_bcnt[b], 1);
        if (pos < BCAP)   // +96 sigma margin; statistically impossible to trip
            g_brec[b][pos] = (unsigned)src[e] | ((unsigned)(d & (BNODES - 1)) << 17);
    }
}

// ---------------- Kernel 3: per-bucket gather with LDS accumulators ----------------
// One block per bucket (64 dst nodes). Records are read SEQUENTIALLY
// (coalesced; the g_ns random-line stream of R6/R8 is gone). The only random
// 64B line left is the z row. Accumulate into LDS via ds_add_f32: lanes hit
// 32 distinct banks (stride 33), no conflict.
__global__ __launch_bounds__(256) void k_gather(float* __restrict__ out, int n_nodes)
{
    __shared__ float accs[BNODES][33];   // stride 33: bank = (d + lane) & 31
    __shared__ float dens[BNODES];
    __shared__ float ers[BNODES];

    int b = blockIdx.x;
    int t = threadIdx.x;
    for (int i = t; i < BNODES * 33; i += 256) ((float*)accs)[i] = 0.f;
    if (t < BNODES) {
        dens[t] = 0.f;
        int gn = (b << BNODES_LOG) + t;
        ers[t] = (gn < n_nodes) ? g_er[gn] : 0.f;
    }
    __syncthreads();

    int cnt = g_bcnt[b];
    if (cnt > BCAP) cnt = BCAP;
    int grp = t >> 5, lane = t & 31;
    const unsigned* rec = g_brec[b];
    const unsigned short* zb = (const unsigned short*)g_zb;

    int j = grp;
    for (; j + 8 < cnt; j += 16) {       // 2 independent records in flight/group
        unsigned r0 = rec[j], r1 = rec[j + 8];
        int s0 = r0 & SRC_MASK, d0 = r0 >> 17;
        int s1 = r1 & SRC_MASK, d1 = r1 >> 17;
        float x0 = g_el[s0] + ers[d0];
        float x1 = g_el[s1] + ers[d1];
        x0 = (x0 > 0.f) ? x0 : NEG_SLOPE_C * x0;
        x1 = (x1 > 0.f) ? x1 : NEG_SLOPE_C * x1;
        float e0 = __expf(x0), e1 = __expf(x1);
        float z0 = bf2f(zb[(size_t)s0 * OUT_FEATS_C + lane]);
        float z1 = bf2f(zb[(size_t)s1 * OUT_FEATS_C + lane]);
        atomicAdd(&accs[d0][lane], e0 * z0);
        atomicAdd(&accs[d1][lane], e1 * z1);
        if (lane == 0) { atomicAdd(&dens[d0], e0); atomicAdd(&dens[d1], e1); }
    }
    for (; j < cnt; j += 8) {
        unsigned r0 = rec[j];
        int s0 = r0 & SRC_MASK, d0 = r0 >> 17;
        float x0 = g_el[s0] + ers[d0];
        x0 = (x0 > 0.f) ? x0 : NEG_SLOPE_C * x0;
        float e0 = __expf(x0);
        float z0 = bf2f(zb[(size_t)s0 * OUT_FEATS_C + lane]);
        atomicAdd(&accs[d0][lane], e0 * z0);
        if (lane == 0) atomicAdd(&dens[d0], e0);
    }
    __syncthreads();

    // epilogue: 64 nodes x 32 feats, coalesced writes
    for (int n = grp; n < BNODES; n += 8) {
        int gn = (b << BNODES_LOG) + n;
        if (gn < n_nodes)
            out[(size_t)gn * OUT_FEATS_C + lane] =
                accs[n][lane] / fmaxf(dens[n], 1e-16f);
    }
}

extern "C" void kernel_launch(void* const* d_in, const int* in_sizes, int n_in,
                              void* d_out, int out_size, void* d_ws, size_t ws_size,
                              hipStream_t stream) {
    const float* h   = (const float*)d_in[0];
    const float* W   = (const float*)d_in[1];
    const float* a   = (const float*)d_in[2];
    const int*   src = (const int*)d_in[3];
    const int*   dst = (const int*)d_in[4];
    float* out = (float*)d_out;

    const int n_nodes = in_sizes[0] / IN_FEATS_C;   // 100000
    const int n_edges = in_sizes[3];                // 1600000
    const int nb = (n_nodes + BNODES - 1) >> BNODES_LOG;  // 1563

    // 0) W fragments + zero bucket counters
    k_wt<<<(NB + 255) / 256, 256, 0, stream>>>(W);
    // 1) MFMA projection (+ el/er)
    {
        int ntiles = (n_nodes + 15) / 16;
        int blocks = (ntiles + 3) / 4;
        k_project<<<blocks, 256, 0, stream>>>(h, a, n_nodes);
    }
    // 2) bucket edges by dst (contiguous per-bucket record regions)
    k_bucket<<<(n_edges + 255) / 256, 256, 0, stream>>>(src, dst, n_edges);
    // 3) per-bucket gather: sequential records, one random z line per edge
    k_gather<<<nb, 256, 0, stream>>>(out, n_nodes);
}

// Round 10
// 217.867 us; speedup vs baseline: 2.6570x; 2.6570x over previous
//
#include <hip/hip_runtime.h>
#include <hip/hip_bf16.h>

#define N_NODES_C  100000
#define N_EDGES_C  1600000
#define IN_FEATS_C 128
#define OUT_FEATS_C 32
#define NEG_SLOPE_C 0.2f

// Segmented chains: edge e lives in segment e>>SEG_SHIFT. Chain hops then
// stay inside a (128k x 8B) = 1MB g_ns window -> L2-resident during the
// gather's per-segment sweep (kills the 8x line amplification of the
// random next-pointer stream; 102 MB -> ~13 MB).
#define SEG_SHIFT  17
#define SEG_SIZE   (1 << SEG_SHIFT)
#define NSEG       ((N_EDGES_C + SEG_SIZE - 1) >> SEG_SHIFT)   // 13

typedef __attribute__((ext_vector_type(8))) short short8;
typedef __attribute__((ext_vector_type(4))) float f32x4;

// Static device scratch (~26 MB) — no assumption about ws_size.
__device__ __hip_bfloat16 g_zb[N_NODES_C * OUT_FEATS_C];  // bf16 z: 64B/row = 1 line/edge
__device__ float  g_el[N_NODES_C];
__device__ float  g_er[N_NODES_C];
__device__ int    g_head[NSEG][N_NODES_C];  // per-(segment,node) chain heads
__device__ int2   g_ns[N_EDGES_C];          // packed {next-in-segment, src}
__device__ short8 g_wf_hi[2][4][64];        // W MFMA B-fragments (bf16 hi)
__device__ short8 g_wf_lo[2][4][64];        // ... lo part (hi+lo split ~ f32 accuracy)

static __device__ __forceinline__ unsigned short f2bf(float x) {
    unsigned int u = __float_as_uint(x);
    unsigned int r = (u + 0x7FFFu + ((u >> 16) & 1u)) >> 16;
    return (unsigned short)r;
}
static __device__ __forceinline__ float bf2f(unsigned short h) {
    return __uint_as_float(((unsigned int)h) << 16);
}

// ---------------- Kernel: init chain heads to -1 (coalesced) ----------------
__global__ __launch_bounds__(256) void k_init(int n)
{
    int i = blockIdx.x * 256 + threadIdx.x;
    if (i < n) ((int*)g_head)[i] = -1;
}

// ---------------- Kernel 0: one-shot W -> MFMA B-fragment build ----------------
__global__ __launch_bounds__(256) void k_wt(const float* __restrict__ W)
{
    int i = blockIdx.x * 256 + threadIdx.x;      // 0..511
    if (i >= 512) return;
    int lane = i & 63;
    int kt   = (i >> 6) & 3;
    int nt   = i >> 8;
    int row  = nt * 16 + (lane & 15);
    const float* p = W + (size_t)row * IN_FEATS_C + kt * 32 + (lane >> 4) * 8;
    float4 x0 = *(const float4*)(p);
    float4 x1 = *(const float4*)(p + 4);
    float xs[8] = {x0.x, x0.y, x0.z, x0.w, x1.x, x1.y, x1.z, x1.w};
    short8 hi, lo;
#pragma unroll
    for (int j = 0; j < 8; ++j) {
        unsigned short hb = f2bf(xs[j]);
        hi[j] = (short)hb;
        lo[j] = (short)f2bf(xs[j] - bf2f(hb));
    }
    g_wf_hi[nt][kt][lane] = hi;
    g_wf_lo[nt][kt][lane] = lo;
}

// ---------------- Kernel 1: MFMA projection (proven, unchanged) ----------------
__global__ __launch_bounds__(256) void k_project(const float* __restrict__ h,
                                                 const float* __restrict__ a,
                                                 int n_nodes)
{
    int tile = (blockIdx.x * 256 + threadIdx.x) >> 6;
    int l    = threadIdx.x & 63;
    int ntiles = (n_nodes + 15) / 16;
    if (tile >= ntiles) return;
    int r16 = l & 15;
    int g   = l >> 4;

    const float* hrow = h + (size_t)(tile * 16 + r16) * IN_FEATS_C + g * 8;
    f32x4 acc0 = {0.f, 0.f, 0.f, 0.f};
    f32x4 acc1 = {0.f, 0.f, 0.f, 0.f};

#pragma unroll
    for (int kt = 0; kt < 4; ++kt) {
        float4 x0 = *(const float4*)(hrow + kt * 32);
        float4 x1 = *(const float4*)(hrow + kt * 32 + 4);
        float xs[8] = {x0.x, x0.y, x0.z, x0.w, x1.x, x1.y, x1.z, x1.w};
        short8 ahi, alo;
#pragma unroll
        for (int j = 0; j < 8; ++j) {
            unsigned short hb = f2bf(xs[j]);
            ahi[j] = (short)hb;
            alo[j] = (short)f2bf(xs[j] - bf2f(hb));
        }
        short8 bh0 = g_wf_hi[0][kt][l], bl0 = g_wf_lo[0][kt][l];
        short8 bh1 = g_wf_hi[1][kt][l], bl1 = g_wf_lo[1][kt][l];
        acc0 = __builtin_amdgcn_mfma_f32_16x16x32_bf16(ahi, bh0, acc0, 0, 0, 0);
        acc0 = __builtin_amdgcn_mfma_f32_16x16x32_bf16(alo, bh0, acc0, 0, 0, 0);
        acc0 = __builtin_amdgcn_mfma_f32_16x16x32_bf16(ahi, bl0, acc0, 0, 0, 0);
        acc1 = __builtin_amdgcn_mfma_f32_16x16x32_bf16(ahi, bh1, acc1, 0, 0, 0);
        acc1 = __builtin_amdgcn_mfma_f32_16x16x32_bf16(alo, bh1, acc1, 0, 0, 0);
        acc1 = __builtin_amdgcn_mfma_f32_16x16x32_bf16(ahi, bl1, acc1, 0, 0, 0);
    }

    float al0 = a[r16], al1 = a[16 + r16];
    float ar0 = a[32 + r16], ar1 = a[48 + r16];
    float elp[4], erp[4];
    unsigned short* zb = (unsigned short*)g_zb;
#pragma unroll
    for (int r = 0; r < 4; ++r) {
        float z0 = acc0[r], z1 = acc1[r];
        int node = tile * 16 + g * 4 + r;
        zb[(size_t)node * OUT_FEATS_C + r16]      = f2bf(z0);
        zb[(size_t)node * OUT_FEATS_C + 16 + r16] = f2bf(z1);
        elp[r] = z0 * al0 + z1 * al1;
        erp[r] = z0 * ar0 + z1 * ar1;
    }
#pragma unroll
    for (int m = 1; m <= 8; m <<= 1) {
#pragma unroll
        for (int r = 0; r < 4; ++r) {
            elp[r] += __shfl_xor(elp[r], m, 64);
            erp[r] += __shfl_xor(erp[r], m, 64);
        }
    }
    int nodeb = tile * 16 + g * 4;
    if (r16 == 0) {
#pragma unroll
        for (int r = 0; r < 4; ++r) g_el[nodeb + r] = elp[r];
    } else if (r16 == 1) {
#pragma unroll
        for (int r = 0; r < 4; ++r) g_er[nodeb + r] = erp[r];
    }
}

// ---------------- Kernel 2: segmented linked-list build ----------------
// The proven-cheap build: ONE random atomic per edge + COALESCED int2 store.
// Segment = e >> 17, so each chain stays inside a 1MB g_ns window.
__global__ __launch_bounds__(256) void k_link(const int* __restrict__ src,
                                              const int* __restrict__ dst, int n_edges)
{
    int e = blockIdx.x * blockDim.x + threadIdx.x;
    if (e < n_edges) {
        int s = e >> SEG_SHIFT;
        int nxt = atomicExch(&g_head[s][dst[e]], e);
        g_ns[e] = make_int2(nxt, src[e]);
    }
}

// ---------------- Kernel 3: gather via per-segment chain sweep ----------------
// 32 lanes per node (lane = feature). All NSEG head loads issued up front
// (independent); then segments processed in order so the ns window sweeps
// 1MB at a time (L2-resident across all concurrent blocks). Avg chain
// length per (seg,node) = 1.3. The only remaining random 64B stream is the
// bf16 z row.
__global__ __launch_bounds__(256) void k_gather(float* __restrict__ out, int n_nodes)
{
    int tid  = blockIdx.x * blockDim.x + threadIdx.x;
    int node = tid >> 5;
    int f    = tid & 31;
    if (node >= n_nodes) return;

    int jj[NSEG];
#pragma unroll
    for (int s = 0; s < NSEG; ++s) jj[s] = g_head[s][node];   // independent loads

    float er_d = g_er[node];
    const unsigned short* zb = (const unsigned short*)g_zb;
    float acc = 0.f, den = 0.f;

#pragma unroll
    for (int s = 0; s < NSEG; ++s) {
        int j = jj[s];
        while (j >= 0) {
            int2 ns = g_ns[j];       // within this segment's 1MB window (L2-hot)
            int sn  = ns.y;
            float x = g_el[sn] + er_d;
            x = (x > 0.f) ? x : NEG_SLOPE_C * x;
            float ex = __expf(x);    // shift-free softmax (logits O(5), safe in f32)
            den += ex;
            acc = fmaf(ex, bf2f(zb[(size_t)sn * OUT_FEATS_C + f]), acc);
            j = ns.x;
        }
    }
    out[(size_t)node * OUT_FEATS_C + f] = acc / fmaxf(den, 1e-16f);
}

extern "C" void kernel_launch(void* const* d_in, const int* in_sizes, int n_in,
                              void* d_out, int out_size, void* d_ws, size_t ws_size,
                              hipStream_t stream) {
    const float* h   = (const float*)d_in[0];
    const float* W   = (const float*)d_in[1];
    const float* a   = (const float*)d_in[2];
    const int*   src = (const int*)d_in[3];
    const int*   dst = (const int*)d_in[4];
    float* out = (float*)d_out;

    const int n_nodes = in_sizes[0] / IN_FEATS_C;   // 100000
    const int n_edges = in_sizes[3];                // 1600000

    // 0) heads = -1 ; W -> bf16 hi/lo MFMA fragments
    k_init<<<(NSEG * n_nodes + 255) / 256, 256, 0, stream>>>(NSEG * n_nodes);
    k_wt<<<2, 256, 0, stream>>>(W);
    // 1) MFMA projection (+ el/er)
    {
        int ntiles = (n_nodes + 15) / 16;
        int blocks = (ntiles + 3) / 4;
        k_project<<<blocks, 256, 0, stream>>>(h, a, n_nodes);
    }
    // 2) segmented linked-list build (single atomic + coalesced record store)
    k_link<<<(n_edges + 255) / 256, 256, 0, stream>>>(src, dst, n_edges);
    // 3) gather: per-segment chain sweep, register accumulation
    k_gather<<<(n_nodes * 32 + 255) / 256, 256, 0, stream>>>(out, n_nodes);
}

// Round 11
// 181.328 us; speedup vs baseline: 3.1924x; 1.2015x over previous
//
#include <hip/hip_runtime.h>
#include <hip/hip_bf16.h>

#define N_NODES_C  100000
#define N_EDGES_C  1600000
#define IN_FEATS_C 128
#define OUT_FEATS_C 32
#define NEG_SLOPE_C 0.2f

typedef __attribute__((ext_vector_type(8))) short short8;
typedef __attribute__((ext_vector_type(4))) float f32x4;

// Static device scratch (~20 MB) — no assumption about ws_size.
__device__ __hip_bfloat16 g_zb[N_NODES_C * OUT_FEATS_C];  // bf16 z: 64B/row = 1 line/edge
__device__ float  g_el[N_NODES_C];
__device__ float  g_er[N_NODES_C];
__device__ int    g_head[N_NODES_C];   // linked-list head per dst node
__device__ int2   g_ns[N_EDGES_C];     // packed {next, src} per edge (coalesced store)
__device__ short8 g_wf_hi[2][4][64];   // W MFMA B-fragments (bf16 hi)
__device__ short8 g_wf_lo[2][4][64];   // ... lo part (hi+lo split ~ f32 accuracy)

static __device__ __forceinline__ unsigned short f2bf(float x) {
    unsigned int u = __float_as_uint(x);
    unsigned int r = (u + 0x7FFFu + ((u >> 16) & 1u)) >> 16;
    return (unsigned short)r;
}
static __device__ __forceinline__ float bf2f(unsigned short h) {
    return __uint_as_float(((unsigned int)h) << 16);
}

// ---------------- Kernel A: prep = head init + W fragment build ----------------
// blocks [0, nbn): g_head = -1 (coalesced). blocks [nbn, nbn+2): W -> bf16
// hi/lo MFMA B-fragments (lane l holds B[k][n], n=l&15, k=(l>>4)*8+j).
__global__ __launch_bounds__(256) void k_prep(const float* __restrict__ W, int n_nodes, int nbn)
{
    int b = blockIdx.x;
    if (b < nbn) {
        int i = b * 256 + threadIdx.x;
        if (i < n_nodes) g_head[i] = -1;      // re-init every call (stateless)
        return;
    }
    int i = (b - nbn) * 256 + threadIdx.x;    // 0..511
    if (i >= 512) return;
    int lane = i & 63;
    int kt   = (i >> 6) & 3;
    int nt   = i >> 8;
    int row  = nt * 16 + (lane & 15);
    const float* p = W + (size_t)row * IN_FEATS_C + kt * 32 + (lane >> 4) * 8;
    float4 x0 = *(const float4*)(p);
    float4 x1 = *(const float4*)(p + 4);
    float xs[8] = {x0.x, x0.y, x0.z, x0.w, x1.x, x1.y, x1.z, x1.w};
    short8 hi, lo;
#pragma unroll
    for (int j = 0; j < 8; ++j) {
        unsigned short hb = f2bf(xs[j]);
        hi[j] = (short)hb;
        lo[j] = (short)f2bf(xs[j] - bf2f(hb));
    }
    g_wf_hi[nt][kt][lane] = hi;
    g_wf_lo[nt][kt][lane] = lo;
}

// ---------------- Kernel B: FAT kernel = MFMA projection ∪ linked-list build ----
// The two phases are data-independent (project: zb/el/er; link: head/ns) and
// stress different pipes (MFMA+VALU vs memory-side atomics). Interleaved 1:4
// by blockIdx so both populations are co-resident -> link's atomic latency
// hides under project's compute (m114: separate pipes overlap ~max not sum).
__global__ __launch_bounds__(256) void k_fat(const float* __restrict__ h,
                                             const float* __restrict__ a,
                                             const int* __restrict__ src,
                                             const int* __restrict__ dst,
                                             int n_nodes, int n_edges,
                                             int PB, int LB)
{
    int bid = blockIdx.x;
    if (bid % 5 == 0) {
        // ---- project role: 4 tiles of 16 nodes per block ----
        int pidx = bid / 5;
        if (pidx >= PB) return;
        int tile = pidx * 4 + (threadIdx.x >> 6);
        int ntiles = (n_nodes + 15) / 16;
        if (tile >= ntiles) return;
        int l   = threadIdx.x & 63;
        int r16 = l & 15;
        int g   = l >> 4;

        const float* hrow = h + (size_t)(tile * 16 + r16) * IN_FEATS_C + g * 8;
        f32x4 acc0 = {0.f, 0.f, 0.f, 0.f};
        f32x4 acc1 = {0.f, 0.f, 0.f, 0.f};

#pragma unroll
        for (int kt = 0; kt < 4; ++kt) {
            float4 x0 = *(const float4*)(hrow + kt * 32);
            float4 x1 = *(const float4*)(hrow + kt * 32 + 4);
            float xs[8] = {x0.x, x0.y, x0.z, x0.w, x1.x, x1.y, x1.z, x1.w};
            short8 ahi, alo;
#pragma unroll
            for (int j = 0; j < 8; ++j) {
                unsigned short hb = f2bf(xs[j]);
                ahi[j] = (short)hb;
                alo[j] = (short)f2bf(xs[j] - bf2f(hb));
            }
            short8 bh0 = g_wf_hi[0][kt][l], bl0 = g_wf_lo[0][kt][l];
            short8 bh1 = g_wf_hi[1][kt][l], bl1 = g_wf_lo[1][kt][l];
            acc0 = __builtin_amdgcn_mfma_f32_16x16x32_bf16(ahi, bh0, acc0, 0, 0, 0);
            acc0 = __builtin_amdgcn_mfma_f32_16x16x32_bf16(alo, bh0, acc0, 0, 0, 0);
            acc0 = __builtin_amdgcn_mfma_f32_16x16x32_bf16(ahi, bl0, acc0, 0, 0, 0);
            acc1 = __builtin_amdgcn_mfma_f32_16x16x32_bf16(ahi, bh1, acc1, 0, 0, 0);
            acc1 = __builtin_amdgcn_mfma_f32_16x16x32_bf16(alo, bh1, acc1, 0, 0, 0);
            acc1 = __builtin_amdgcn_mfma_f32_16x16x32_bf16(ahi, bl1, acc1, 0, 0, 0);
        }

        float al0 = a[r16], al1 = a[16 + r16];
        float ar0 = a[32 + r16], ar1 = a[48 + r16];
        float elp[4], erp[4];
        unsigned short* zb = (unsigned short*)g_zb;
#pragma unroll
        for (int r = 0; r < 4; ++r) {
            float z0 = acc0[r], z1 = acc1[r];
            int node = tile * 16 + g * 4 + r;
            zb[(size_t)node * OUT_FEATS_C + r16]      = f2bf(z0);
            zb[(size_t)node * OUT_FEATS_C + 16 + r16] = f2bf(z1);
            elp[r] = z0 * al0 + z1 * al1;
            erp[r] = z0 * ar0 + z1 * ar1;
        }
#pragma unroll
        for (int m = 1; m <= 8; m <<= 1) {
#pragma unroll
            for (int r = 0; r < 4; ++r) {
                elp[r] += __shfl_xor(elp[r], m, 64);
                erp[r] += __shfl_xor(erp[r], m, 64);
            }
        }
        int nodeb = tile * 16 + g * 4;
        if (r16 == 0) {
#pragma unroll
            for (int r = 0; r < 4; ++r) g_el[nodeb + r] = elp[r];
        } else if (r16 == 1) {
#pragma unroll
            for (int r = 0; r < 4; ++r) g_er[nodeb + r] = erp[r];
        }
    } else {
        // ---- link role: 1 edge per thread ----
        int lidx = 4 * (bid / 5) + (bid % 5) - 1;
        if (lidx >= LB) return;
        int e = lidx * 256 + threadIdx.x;
        if (e < n_edges) {
            int nxt = atomicExch(&g_head[dst[e]], e);   // ONE random atomic/edge
            g_ns[e] = make_int2(nxt, src[e]);           // coalesced record store
        }
    }
}

// ---------------- Kernel C: per-node gather via chain walk (R6 champion) ----------------
// 32 lanes per node (lane = feature). Per edge: one packed int2 record line +
// one 64B bf16 z-row line (+ el, mostly L2). ~2 TB/s scattered-line wall.
__global__ __launch_bounds__(256) void k_gather(float* __restrict__ out, int n_nodes)
{
    int tid  = blockIdx.x * blockDim.x + threadIdx.x;
    int node = tid >> 5;
    int f    = tid & 31;
    if (node >= n_nodes) return;

    float er_d = g_er[node];
    const unsigned short* zb = (const unsigned short*)g_zb;
    float acc = 0.f, den = 0.f;
    int j = g_head[node];
    while (j >= 0) {
        int2 ns = g_ns[j];       // {next, src} in one line
        int s   = ns.y;
        float x = g_el[s] + er_d;
        x = (x > 0.f) ? x : NEG_SLOPE_C * x;
        float ex = __expf(x);    // shift-free softmax (logits O(5), safe in f32)
        den += ex;
        acc = fmaf(ex, bf2f(zb[(size_t)s * OUT_FEATS_C + f]), acc);
        j = ns.x;
    }
    out[(size_t)node * OUT_FEATS_C + f] = acc / fmaxf(den, 1e-16f);
}

extern "C" void kernel_launch(void* const* d_in, const int* in_sizes, int n_in,
                              void* d_out, int out_size, void* d_ws, size_t ws_size,
                              hipStream_t stream) {
    const float* h   = (const float*)d_in[0];
    const float* W   = (const float*)d_in[1];
    const float* a   = (const float*)d_in[2];
    const int*   src = (const int*)d_in[3];
    const int*   dst = (const int*)d_in[4];
    float* out = (float*)d_out;

    const int n_nodes = in_sizes[0] / IN_FEATS_C;   // 100000
    const int n_edges = in_sizes[3];                // 1600000

    const int nbn    = (n_nodes + 255) / 256;       // 391 head-init blocks
    const int ntiles = (n_nodes + 15) / 16;         // 6250
    const int PB     = (ntiles + 3) / 4;            // 1563 project blocks
    const int LB     = (n_edges + 255) / 256;       // 6250 link blocks
    const int G      = 5 * ((PB > (LB + 3) / 4) ? PB : (LB + 3) / 4);  // covers both roles

    // A) head=-1 + W fragments (one small kernel)
    k_prep<<<nbn + 2, 256, 0, stream>>>(W, n_nodes, nbn);
    // B) fat kernel: projection ∪ linked-list build, co-resident
    k_fat<<<G, 256, 0, stream>>>(h, a, src, dst, n_nodes, n_edges, PB, LB);
    // C) gather (writes every output element exactly once)
    k_gather<<<(n_nodes * 32 + 255) / 256, 256, 0, stream>>>(out, n_nodes);
}